// Round 6
// baseline (226.957 us; speedup 1.0000x reference)
//
#include <hip/hip_runtime.h>

// SSIM loss, fused single-pass separable box filter — shuffle halo, no atomics.
// R6: R5's body, finer decomposition. SH=8 -> 4, 1024 -> 2048 blocks, so up to
// ~24 waves/CU resident (vs ~8 measured in R5) to hide the per-row load
// latency (~900cyc HBM add-row + ~500cyc L3 sub-row) that R5's 30% VALUBusy
// shows is still exposed. Halo warm-up amplification (10 extra rows per wave)
// is absorbed by L3 (full 128 MiB dataset fits in 256 MiB).
//
// Grid: 2048 blocks = 64 images x 32 row-bands. Block = 256 threads = 4
// independent waves. Each wave owns SH=4 output rows x 512 cols; each lane
// owns 8 contiguous columns. Vertical 11-row window: per-lane register
// running sums (slide add/sub). Horizontal: 5-float halo per side via __shfl.

#define IMG_H 512
#define IMG_W 512
#define N_IMG 64
#define RAD   5
#define SH    4
#define NBAND 32
#define NBLOCKS (N_IMG * NBAND)

#define C1_SSIM 1.0e-4f
#define C2_SSIM 9.0e-4f

__global__ __launch_bounds__(256) void ssim_fused(const float* __restrict__ x,
                                                  const float* __restrict__ y,
                                                  float* __restrict__ part)
{
    const int tx  = threadIdx.x & 63;
    const int ts  = threadIdx.x >> 6;
    const int img = blockIdx.x >> 5;          // / NBAND
    const int bnd = blockIdx.x & (NBAND - 1);
    const int r0  = bnd * (4 * SH) + ts * SH;
    const int c0  = tx * 8;

    const float* __restrict__ xb = x + (size_t)img * (IMG_H * IMG_W) + c0;
    const float* __restrict__ yb = y + (size_t)img * (IMG_H * IMG_W) + c0;

    float Vx[8], Vy[8], Vxx[8], Vyy[8], Vxy[8];
#pragma unroll
    for (int j = 0; j < 8; ++j) { Vx[j] = 0.f; Vy[j] = 0.f; Vxx[j] = 0.f; Vyy[j] = 0.f; Vxy[j] = 0.f; }

    // add or subtract one input row into the running vertical sums
    auto accum = [&](int ri, bool add) {
        const float4* xr = (const float4*)(xb + (size_t)ri * IMG_W);
        const float4* yr = (const float4*)(yb + (size_t)ri * IMG_W);
        float4 x0 = xr[0], x1 = xr[1];
        float4 y0 = yr[0], y1 = yr[1];
        float xs[8] = {x0.x, x0.y, x0.z, x0.w, x1.x, x1.y, x1.z, x1.w};
        float ys[8] = {y0.x, y0.y, y0.z, y0.w, y1.x, y1.y, y1.z, y1.w};
        if (add) {
#pragma unroll
            for (int j = 0; j < 8; ++j) {
                Vx[j]  += xs[j];
                Vy[j]  += ys[j];
                Vxx[j] = fmaf(xs[j], xs[j], Vxx[j]);
                Vyy[j] = fmaf(ys[j], ys[j], Vyy[j]);
                Vxy[j] = fmaf(xs[j], ys[j], Vxy[j]);
            }
        } else {
#pragma unroll
            for (int j = 0; j < 8; ++j) {
                Vx[j]  -= xs[j];
                Vy[j]  -= ys[j];
                Vxx[j] = fmaf(-xs[j], xs[j], Vxx[j]);
                Vyy[j] = fmaf(-ys[j], ys[j], Vyy[j]);
                Vxy[j] = fmaf(-xs[j], ys[j], Vxy[j]);
            }
        }
    };

    // 11-tap sliding horizontal sums; halo via lane+-1 shuffles
    auto hsum = [&](const float (&V)[8], float (&S)[8]) {
        float w[18];
#pragma unroll
        for (int k = 0; k < 5; ++k) {
            float l = __shfl_up(V[3 + k], 1, 64);
            w[k] = (tx == 0) ? 0.f : l;
        }
#pragma unroll
        for (int j = 0; j < 8; ++j) w[5 + j] = V[j];
#pragma unroll
        for (int k = 0; k < 5; ++k) {
            float r = __shfl_down(V[k], 1, 64);
            w[13 + k] = (tx == 63) ? 0.f : r;
        }
        float s = 0.f;
#pragma unroll
        for (int t = 0; t < 11; ++t) s += w[t];
        S[0] = s;
#pragma unroll
        for (int j = 1; j < 8; ++j) { s += w[j + 10] - w[j - 1]; S[j] = s; }
    };

    // warm-up: rows [r0-5, r0+4] (invariant: V holds rows ro-5..ro+4 at loop head)
    for (int ri = r0 - RAD; ri < r0 + RAD; ++ri)
        if (ri >= 0 && ri < IMG_H) accum(ri, true);

    const float inv121 = 1.0f / 121.0f;
    float loss = 0.0f;

#pragma unroll
    for (int ro = r0; ro < r0 + SH; ++ro) {
        int ra = ro + RAD;
        if (ra < IMG_H) accum(ra, true);

        float Sx[8], Sy[8], Sxx[8], Syy[8], Sxy[8];
        hsum(Vx,  Sx);
        hsum(Vy,  Sy);
        hsum(Vxx, Sxx);
        hsum(Vyy, Syy);
        hsum(Vxy, Sxy);

#pragma unroll
        for (int j = 0; j < 8; ++j) {
            float mx  = Sx[j] * inv121;
            float my  = Sy[j] * inv121;
            float mx2 = mx * mx;
            float my2 = my * my;
            float mxy = mx * my;
            float vx  = Sxx[j] * inv121 - mx2;
            float vy  = Syy[j] * inv121 - my2;
            float vxy = Sxy[j] * inv121 - mxy;
            float num = (2.0f * mxy + C1_SSIM) * (2.0f * vxy + C2_SSIM);
            float den = (mx2 + my2 + C1_SSIM) * (vx + vy + C2_SSIM);
            loss += __fdividef(num, den);
        }

        int rs = ro - RAD;
        if (rs >= 0) accum(rs, false);
    }

    // reduction: wave shfl-reduce -> LDS -> one plain store per block.
#pragma unroll
    for (int off = 32; off > 0; off >>= 1)
        loss += __shfl_down(loss, off, 64);

    __shared__ float pr[4];
    if (tx == 0) pr[ts] = loss;
    __syncthreads();
    if (threadIdx.x == 0)
        part[blockIdx.x] = (pr[0] + pr[1]) + (pr[2] + pr[3]);
}

// single-block finisher: reduce 2048 partials (8 KB) and write the loss
__global__ __launch_bounds__(256) void ssim_reduce(const float* __restrict__ part,
                                                   float* __restrict__ out)
{
    const int t  = threadIdx.x;
    const int tx = t & 63;
    float s = 0.f;
#pragma unroll
    for (int k = 0; k < NBLOCKS / 256; ++k)
        s += part[t + k * 256];
#pragma unroll
    for (int off = 32; off > 0; off >>= 1)
        s += __shfl_down(s, off, 64);
    __shared__ float ws[4];
    if (tx == 0) ws[t >> 6] = s;
    __syncthreads();
    if (t == 0) {
        float total = (ws[0] + ws[1]) + (ws[2] + ws[3]);
        out[0] = 1.0f - total * (1.0f / ((float)N_IMG * IMG_H * IMG_W));
    }
}

extern "C" void kernel_launch(void* const* d_in, const int* in_sizes, int n_in,
                              void* d_out, int out_size, void* d_ws, size_t ws_size,
                              hipStream_t stream) {
    const float* x = (const float*)d_in[0];
    const float* y = (const float*)d_in[1];
    // d_in[2] is the uniform 11x11/121 kernel; its value is compile-time known.
    float* part = (float*)d_ws;           // 2048 floats, all written each call

    ssim_fused<<<NBLOCKS, 256, 0, stream>>>(x, y, part);
    ssim_reduce<<<1, 256, 0, stream>>>(part, (float*)d_out);
}

// Round 7
// 190.495 us; speedup vs baseline: 1.1914x; 1.1914x over previous
//
#include <hip/hip_runtime.h>

// SSIM loss, fused single-pass separable box filter — shuffle halo, no atomics.
// R7: R6's finer decomposition done right. R6's `#pragma unroll` blew VGPRs
// to 168 (occupancy 11%) via cross-iteration load CSE; here the row loop is
// pinned to unroll-1 so VGPR stays ~<=128 and 2048 blocks actually buy
// residency (8 blocks/CU nominal). Sub-row load is issued at iteration top
// and consumed after hsum+SSIM (~1200 cyc of independent VALU in between).
//
// Grid: 2048 blocks = 64 images x 32 row-bands. Block = 256 threads = 4
// independent waves. Each wave owns SH=4 output rows x 512 cols; each lane
// owns 8 contiguous columns. Vertical 11-row window: per-lane register
// running sums (slide add/sub). Horizontal: 5-float halo per side via __shfl.

#define IMG_H 512
#define IMG_W 512
#define N_IMG 64
#define RAD   5
#define SH    4
#define NBAND 32
#define NBLOCKS (N_IMG * NBAND)

#define C1_SSIM 1.0e-4f
#define C2_SSIM 9.0e-4f

__global__ __launch_bounds__(256) void ssim_fused(const float* __restrict__ x,
                                                  const float* __restrict__ y,
                                                  float* __restrict__ part)
{
    const int tx  = threadIdx.x & 63;
    const int ts  = threadIdx.x >> 6;
    const int img = blockIdx.x >> 5;          // / NBAND
    const int bnd = blockIdx.x & (NBAND - 1);
    const int r0  = bnd * (4 * SH) + ts * SH;
    const int c0  = tx * 8;

    const float* __restrict__ xb = x + (size_t)img * (IMG_H * IMG_W) + c0;
    const float* __restrict__ yb = y + (size_t)img * (IMG_H * IMG_W) + c0;

    float Vx[8], Vy[8], Vxx[8], Vyy[8], Vxy[8];
#pragma unroll
    for (int j = 0; j < 8; ++j) { Vx[j] = 0.f; Vy[j] = 0.f; Vxx[j] = 0.f; Vyy[j] = 0.f; Vxy[j] = 0.f; }

    // add one input row into the running vertical sums
    auto accum_add = [&](int ri) {
        const float4* xr = (const float4*)(xb + (size_t)ri * IMG_W);
        const float4* yr = (const float4*)(yb + (size_t)ri * IMG_W);
        float4 x0 = xr[0], x1 = xr[1];
        float4 y0 = yr[0], y1 = yr[1];
        float xs[8] = {x0.x, x0.y, x0.z, x0.w, x1.x, x1.y, x1.z, x1.w};
        float ys[8] = {y0.x, y0.y, y0.z, y0.w, y1.x, y1.y, y1.z, y1.w};
#pragma unroll
        for (int j = 0; j < 8; ++j) {
            Vx[j]  += xs[j];
            Vy[j]  += ys[j];
            Vxx[j] = fmaf(xs[j], xs[j], Vxx[j]);
            Vyy[j] = fmaf(ys[j], ys[j], Vyy[j]);
            Vxy[j] = fmaf(xs[j], ys[j], Vxy[j]);
        }
    };

    // 11-tap sliding horizontal sums; halo via lane+-1 shuffles
    auto hsum = [&](const float (&V)[8], float (&S)[8]) {
        float w[18];
#pragma unroll
        for (int k = 0; k < 5; ++k) {
            float l = __shfl_up(V[3 + k], 1, 64);
            w[k] = (tx == 0) ? 0.f : l;
        }
#pragma unroll
        for (int j = 0; j < 8; ++j) w[5 + j] = V[j];
#pragma unroll
        for (int k = 0; k < 5; ++k) {
            float r = __shfl_down(V[k], 1, 64);
            w[13 + k] = (tx == 63) ? 0.f : r;
        }
        float s = 0.f;
#pragma unroll
        for (int t = 0; t < 11; ++t) s += w[t];
        S[0] = s;
#pragma unroll
        for (int j = 1; j < 8; ++j) { s += w[j + 10] - w[j - 1]; S[j] = s; }
    };

    // warm-up: rows [r0-5, r0+4] (invariant: V holds rows ro-5..ro+4 at loop head)
#pragma unroll 1
    for (int ri = r0 - RAD; ri < r0 + RAD; ++ri)
        if (ri >= 0 && ri < IMG_H) accum_add(ri);

    const float inv121 = 1.0f / 121.0f;
    float loss = 0.0f;

#pragma unroll 1
    for (int ro = r0; ro < r0 + SH; ++ro) {
        int ra = ro + RAD;
        if (ra < IMG_H) accum_add(ra);

        // early-issue this iteration's sub-row load; consumed after hsum+SSIM
        int  rs      = ro - RAD;
        bool haveSub = (rs >= 0);               // wave-uniform
        float4 sx0, sx1, sy0, sy1;
        if (haveSub) {
            const float4* xr = (const float4*)(xb + (size_t)rs * IMG_W);
            const float4* yr = (const float4*)(yb + (size_t)rs * IMG_W);
            sx0 = xr[0]; sx1 = xr[1]; sy0 = yr[0]; sy1 = yr[1];
        }

        float Sx[8], Sy[8], Sxx[8], Syy[8], Sxy[8];
        hsum(Vx,  Sx);
        hsum(Vy,  Sy);
        hsum(Vxx, Sxx);
        hsum(Vyy, Syy);
        hsum(Vxy, Sxy);

#pragma unroll
        for (int j = 0; j < 8; ++j) {
            float mx  = Sx[j] * inv121;
            float my  = Sy[j] * inv121;
            float mx2 = mx * mx;
            float my2 = my * my;
            float mxy = mx * my;
            float vx  = Sxx[j] * inv121 - mx2;
            float vy  = Syy[j] * inv121 - my2;
            float vxy = Sxy[j] * inv121 - mxy;
            float num = (2.0f * mxy + C1_SSIM) * (2.0f * vxy + C2_SSIM);
            float den = (mx2 + my2 + C1_SSIM) * (vx + vy + C2_SSIM);
            loss += __fdividef(num, den);
        }

        if (haveSub) {
            float xs[8] = {sx0.x, sx0.y, sx0.z, sx0.w, sx1.x, sx1.y, sx1.z, sx1.w};
            float ys[8] = {sy0.x, sy0.y, sy0.z, sy0.w, sy1.x, sy1.y, sy1.z, sy1.w};
#pragma unroll
            for (int j = 0; j < 8; ++j) {
                Vx[j]  -= xs[j];
                Vy[j]  -= ys[j];
                Vxx[j] = fmaf(-xs[j], xs[j], Vxx[j]);
                Vyy[j] = fmaf(-ys[j], ys[j], Vyy[j]);
                Vxy[j] = fmaf(-xs[j], ys[j], Vxy[j]);
            }
        }
    }

    // reduction: wave shfl-reduce -> LDS -> one plain store per block.
#pragma unroll
    for (int off = 32; off > 0; off >>= 1)
        loss += __shfl_down(loss, off, 64);

    __shared__ float pr[4];
    if (tx == 0) pr[ts] = loss;
    __syncthreads();
    if (threadIdx.x == 0)
        part[blockIdx.x] = (pr[0] + pr[1]) + (pr[2] + pr[3]);
}

// single-block finisher: reduce 2048 partials (8 KB) and write the loss
__global__ __launch_bounds__(256) void ssim_reduce(const float* __restrict__ part,
                                                   float* __restrict__ out)
{
    const int t  = threadIdx.x;
    const int tx = t & 63;
    float s = 0.f;
#pragma unroll
    for (int k = 0; k < NBLOCKS / 256; ++k)
        s += part[t + k * 256];
#pragma unroll
    for (int off = 32; off > 0; off >>= 1)
        s += __shfl_down(s, off, 64);
    __shared__ float ws[4];
    if (tx == 0) ws[t >> 6] = s;
    __syncthreads();
    if (t == 0) {
        float total = (ws[0] + ws[1]) + (ws[2] + ws[3]);
        out[0] = 1.0f - total * (1.0f / ((float)N_IMG * IMG_H * IMG_W));
    }
}

extern "C" void kernel_launch(void* const* d_in, const int* in_sizes, int n_in,
                              void* d_out, int out_size, void* d_ws, size_t ws_size,
                              hipStream_t stream) {
    const float* x = (const float*)d_in[0];
    const float* y = (const float*)d_in[1];
    // d_in[2] is the uniform 11x11/121 kernel; its value is compile-time known.
    float* part = (float*)d_ws;           // 2048 floats, all written each call

    ssim_fused<<<NBLOCKS, 256, 0, stream>>>(x, y, part);
    ssim_reduce<<<1, 256, 0, stream>>>(part, (float*)d_out);
}

// Round 8
// 173.150 us; speedup vs baseline: 1.3108x; 1.1002x over previous
//
#include <hip/hip_runtime.h>
#include <stdint.h>

// SSIM loss — fused separable box filter. R8: add-row staged via
// __builtin_amdgcn_global_load_lds (2-slot per-wave LDS ring, 1-iteration
// prefetch). Rationale: R3/R4/R6 showed the register allocator sinks any
// register-level prefetch; a LDS-DMA has no register result so it cannot be
// sunk, and the vmcnt drain at the consuming ds_read is ~free because the
// last DMA was issued a full iteration (~1500 cyc) earlier. SH=16 tall
// strips cut vmem touch amplification 4.5x -> 2.6x (per-CU miss path was the
// saturated resource: ~11 GB/s/CU = Little's-law cap).
//
// Grid: 512 blocks = 64 images x 8 band-groups; block = 4 waves, wave owns
// SH=16 rows x 512 cols (lane owns 8 cols). Vertical 11-row window via
// per-lane running sums (add staged row / subtract direct re-read).
// Horizontal 11-col window: 5-float halo per side via __shfl.

#define IMG_H 512
#define IMG_W 512
#define N_IMG 64
#define RAD   5
#define SH    16
#define NBANDG 8
#define NBLOCKS (N_IMG * NBANDG)   // 512

#define C1_SSIM 1.0e-4f
#define C2_SSIM 9.0e-4f

#define SLOT_BYTES 4096            // x row (2048 B) + y row (2048 B)

typedef __attribute__((address_space(3))) uint32_t lds_u32_t;
typedef const __attribute__((address_space(1))) uint32_t glb_u32_t;

__device__ __forceinline__ void dma16(void* lds, const void* g) {
    // 64 lanes x 16 B: LDS dest = wave-uniform base + lane*16 (m104/m108)
    __builtin_amdgcn_global_load_lds((glb_u32_t*)g, (lds_u32_t*)lds, 16, 0, 0);
}

__global__ __launch_bounds__(256) void ssim_fused(const float* __restrict__ x,
                                                  const float* __restrict__ y,
                                                  float* __restrict__ part)
{
    __shared__ __align__(16) char ring[4][2][SLOT_BYTES];   // [wave][slot][x|y]

    const int tx  = threadIdx.x & 63;
    const int ts  = threadIdx.x >> 6;
    const int img = blockIdx.x >> 3;            // / NBANDG
    const int bg  = blockIdx.x & (NBANDG - 1);
    const int r0  = bg * (4 * SH) + ts * SH;
    const int c0  = tx * 8;

    const float* __restrict__ xi = x + (size_t)img * (IMG_H * IMG_W);
    const float* __restrict__ yi = y + (size_t)img * (IMG_H * IMG_W);

    // DMA one (x,y) row pair into slot s; returns 0/1 edge scale.
    // Clamped rows load valid data; sc=0 zeroes their contribution.
    auto dma_row = [&](char* s, int ri) -> float {
        int rc = ri < 0 ? 0 : (ri > IMG_H - 1 ? IMG_H - 1 : ri);
        float sc = (ri >= 0 && ri < IMG_H) ? 1.0f : 0.0f;
        const char* xg = (const char*)(xi + (size_t)rc * IMG_W) + tx * 16;
        const char* yg = (const char*)(yi + (size_t)rc * IMG_W) + tx * 16;
        dma16(s,        xg);
        dma16(s + 1024, xg + 1024);
        dma16(s + 2048, yg);
        dma16(s + 3072, yg + 1024);
        return sc;
    };

    float Vx[8], Vy[8], Vxx[8], Vyy[8], Vxy[8];
#pragma unroll
    for (int j = 0; j < 8; ++j) { Vx[j] = 0.f; Vy[j] = 0.f; Vxx[j] = 0.f; Vyy[j] = 0.f; Vxy[j] = 0.f; }

    // read staged row from LDS and add f * (row moments); f = sc (0 or 1)
    auto accum_lds = [&](const char* s, float f) {
        const float4* xr = (const float4*)(s + (size_t)tx * 32);
        const float4* yr = (const float4*)(s + 2048 + (size_t)tx * 32);
        float4 x0 = xr[0], x1 = xr[1];
        float4 y0 = yr[0], y1 = yr[1];
        float xs[8] = {x0.x, x0.y, x0.z, x0.w, x1.x, x1.y, x1.z, x1.w};
        float ys[8] = {y0.x, y0.y, y0.z, y0.w, y1.x, y1.y, y1.z, y1.w};
#pragma unroll
        for (int j = 0; j < 8; ++j) {
            float fx = f * xs[j];
            float fy = f * ys[j];
            Vx[j] += fx;
            Vy[j] += fy;
            Vxx[j] = fmaf(fx, xs[j], Vxx[j]);
            Vyy[j] = fmaf(fy, ys[j], Vyy[j]);
            Vxy[j] = fmaf(fx, ys[j], Vxy[j]);
        }
    };

    // 11-tap sliding horizontal sums; halo via lane+-1 shuffles
    auto hsum = [&](const float (&V)[8], float (&S)[8]) {
        float w[18];
#pragma unroll
        for (int k = 0; k < 5; ++k) {
            float l = __shfl_up(V[3 + k], 1, 64);
            w[k] = (tx == 0) ? 0.f : l;
        }
#pragma unroll
        for (int j = 0; j < 8; ++j) w[5 + j] = V[j];
#pragma unroll
        for (int k = 0; k < 5; ++k) {
            float r = __shfl_down(V[k], 1, 64);
            w[13 + k] = (tx == 63) ? 0.f : r;
        }
        float s = 0.f;
#pragma unroll
        for (int t = 0; t < 11; ++t) s += w[t];
        S[0] = s;
#pragma unroll
        for (int j = 1; j < 8; ++j) { s += w[j + 10] - w[j - 1]; S[j] = s; }
    };

    char* cur = &ring[ts][0][0];
    char* nxt = &ring[ts][1][0];

    // ---- warm-up: apply rows r0-5 .. r0+4 through the DMA double-buffer ----
    float scCur = dma_row(cur, r0 - 5);
#pragma unroll 1
    for (int i = 0; i < 2 * RAD; ++i) {
        accum_lds(cur, scCur);                    // row r0-5+i
        float scN = dma_row(nxt, r0 - 4 + i);     // last issues row r0+5
        char* t = cur; cur = nxt; nxt = t;
        scCur = scN;
    }
    // invariant: cur's slot holds row ro+5 (DMA'd one iteration ago)

    const float inv121 = 1.0f / 121.0f;
    float loss = 0.0f;

#pragma unroll 1
    for (int ro = r0; ro < r0 + SH; ++ro) {
        accum_lds(cur, scCur);                    // add row ro+5 (from LDS)
        float scN = dma_row(nxt, ro + 6);         // prefetch next add row

        // early-issue this iteration's sub-row (direct global, L2/L3-hit);
        // consumed after hsum+SSIM
        int  rs      = ro - RAD;
        bool haveSub = (rs >= 0);                 // wave-uniform
        float4 sx0, sx1, sy0, sy1;
        if (haveSub) {
            const float4* xr = (const float4*)(xi + (size_t)rs * IMG_W + c0);
            const float4* yr = (const float4*)(yi + (size_t)rs * IMG_W + c0);
            sx0 = xr[0]; sx1 = xr[1]; sy0 = yr[0]; sy1 = yr[1];
        }

        float Sx[8], Sy[8], Sxx[8], Syy[8], Sxy[8];
        hsum(Vx,  Sx);
        hsum(Vy,  Sy);
        hsum(Vxx, Sxx);
        hsum(Vyy, Syy);
        hsum(Vxy, Sxy);

#pragma unroll
        for (int j = 0; j < 8; ++j) {
            float mx  = Sx[j] * inv121;
            float my  = Sy[j] * inv121;
            float mx2 = mx * mx;
            float my2 = my * my;
            float mxy = mx * my;
            float vx  = Sxx[j] * inv121 - mx2;
            float vy  = Syy[j] * inv121 - my2;
            float vxy = Sxy[j] * inv121 - mxy;
            float num = (2.0f * mxy + C1_SSIM) * (2.0f * vxy + C2_SSIM);
            float den = (mx2 + my2 + C1_SSIM) * (vx + vy + C2_SSIM);
            loss += __fdividef(num, den);
        }

        if (haveSub) {
            float xs[8] = {sx0.x, sx0.y, sx0.z, sx0.w, sx1.x, sx1.y, sx1.z, sx1.w};
            float ys[8] = {sy0.x, sy0.y, sy0.z, sy0.w, sy1.x, sy1.y, sy1.z, sy1.w};
#pragma unroll
            for (int j = 0; j < 8; ++j) {
                Vx[j]  -= xs[j];
                Vy[j]  -= ys[j];
                Vxx[j] = fmaf(-xs[j], xs[j], Vxx[j]);
                Vyy[j] = fmaf(-ys[j], ys[j], Vyy[j]);
                Vxy[j] = fmaf(-xs[j], ys[j], Vxy[j]);
            }
        }

        char* t = cur; cur = nxt; nxt = t;
        scCur = scN;
    }

    // reduction: wave shfl-reduce -> LDS -> one plain store per block
#pragma unroll
    for (int off = 32; off > 0; off >>= 1)
        loss += __shfl_down(loss, off, 64);

    __shared__ float pr[4];
    if (tx == 0) pr[ts] = loss;
    __syncthreads();
    if (threadIdx.x == 0)
        part[blockIdx.x] = (pr[0] + pr[1]) + (pr[2] + pr[3]);
}

// single-block finisher: reduce 512 partials (2 KB) and write the loss
__global__ __launch_bounds__(256) void ssim_reduce(const float* __restrict__ part,
                                                   float* __restrict__ out)
{
    const int t  = threadIdx.x;
    const int tx = t & 63;
    float s = part[t] + part[t + 256];
#pragma unroll
    for (int off = 32; off > 0; off >>= 1)
        s += __shfl_down(s, off, 64);
    __shared__ float ws[4];
    if (tx == 0) ws[t >> 6] = s;
    __syncthreads();
    if (t == 0) {
        float total = (ws[0] + ws[1]) + (ws[2] + ws[3]);
        out[0] = 1.0f - total * (1.0f / ((float)N_IMG * IMG_H * IMG_W));
    }
}

extern "C" void kernel_launch(void* const* d_in, const int* in_sizes, int n_in,
                              void* d_out, int out_size, void* d_ws, size_t ws_size,
                              hipStream_t stream) {
    const float* x = (const float*)d_in[0];
    const float* y = (const float*)d_in[1];
    // d_in[2] is the uniform 11x11/121 kernel; its value is compile-time known.
    float* part = (float*)d_ws;            // 512 floats, all written each call

    ssim_fused<<<NBLOCKS, 256, 0, stream>>>(x, y, part);
    ssim_reduce<<<1, 256, 0, stream>>>(part, (float*)d_out);
}